// Round 1
// baseline (238.685 us; speedup 1.0000x reference)
//
#include <hip/hip_runtime.h>

// ShortConvolution: depthwise causal conv1d (K=4) + SiLU
// x: (B=4, T=4096, D=2048) fp32, weight: (D, K) fp32, out: (B, T, D) fp32
// y[b,t,d] = silu( sum_k w[d,k] * x[b, t-3+k, d] )   (x[t<0] = 0)

#define B_DIM 4
#define T_DIM 4096
#define D_DIM 2048
#define K_DIM 4
#define TC    16               // timesteps per block (register sliding window)

__global__ __launch_bounds__(512) void shortconv_silu_kernel(
    const float* __restrict__ x,
    const float* __restrict__ w,
    float* __restrict__ out)
{
    const int n_chunks = T_DIM / TC;          // 256
    const int b  = blockIdx.x / n_chunks;
    const int c  = blockIdx.x % n_chunks;
    const int t0 = c * TC;
    const int d4 = threadIdx.x;               // float4 index over D: 512 covers 2048
    const int d0 = d4 * 4;

    // Per-thread weights: 4 channels x 4 taps = 16 consecutive floats (row-major (D,K))
    const float4 q0 = *(const float4*)(w + (size_t)(d0 + 0) * K_DIM);
    const float4 q1 = *(const float4*)(w + (size_t)(d0 + 1) * K_DIM);
    const float4 q2 = *(const float4*)(w + (size_t)(d0 + 2) * K_DIM);
    const float4 q3 = *(const float4*)(w + (size_t)(d0 + 3) * K_DIM);

    const int rowstride = D_DIM / 4;          // float4 elements per time row
    const float4* xv = (const float4*)(x   + (size_t)b * T_DIM * D_DIM) + d4;
    float4*       ov = (float4*)      (out + (size_t)b * T_DIM * D_DIM) + d4;

    // Sliding window registers: w0=x[t-3], w1=x[t-2], w2=x[t-1], w3=x[t]
    float4 w0, w1, w2, w3;
    if (c == 0) {
        w0 = make_float4(0.f, 0.f, 0.f, 0.f);
        w1 = w0;
        w2 = w0;
    } else {
        w0 = xv[(size_t)(t0 - 3) * rowstride];
        w1 = xv[(size_t)(t0 - 2) * rowstride];
        w2 = xv[(size_t)(t0 - 1) * rowstride];
    }

#pragma unroll
    for (int i = 0; i < TC; ++i) {
        w3 = xv[(size_t)(t0 + i) * rowstride];

        float4 y;
        y.x = q0.x * w0.x + q0.y * w1.x + q0.z * w2.x + q0.w * w3.x;
        y.y = q1.x * w0.y + q1.y * w1.y + q1.z * w2.y + q1.w * w3.y;
        y.z = q2.x * w0.z + q2.y * w1.z + q2.z * w2.z + q2.w * w3.z;
        y.w = q3.x * w0.w + q3.y * w1.w + q3.z * w2.w + q3.w * w3.w;

        // SiLU: y * sigmoid(y) = y / (1 + exp(-y))
        y.x = y.x / (1.f + __expf(-y.x));
        y.y = y.y / (1.f + __expf(-y.y));
        y.z = y.z / (1.f + __expf(-y.z));
        y.w = y.w / (1.f + __expf(-y.w));

        ov[(size_t)(t0 + i) * rowstride] = y;

        w0 = w1;
        w1 = w2;
        w2 = w3;
    }
}

extern "C" void kernel_launch(void* const* d_in, const int* in_sizes, int n_in,
                              void* d_out, int out_size, void* d_ws, size_t ws_size,
                              hipStream_t stream) {
    const float* x = (const float*)d_in[0];
    const float* w = (const float*)d_in[1];
    float* out = (float*)d_out;

    const int n_chunks = T_DIM / TC;            // 256
    dim3 grid(B_DIM * n_chunks);                // 1024 blocks
    dim3 block(D_DIM / 4);                      // 512 threads
    shortconv_silu_kernel<<<grid, block, 0, stream>>>(x, w, out);
}

// Round 2
// 230.692 us; speedup vs baseline: 1.0347x; 1.0347x over previous
//
#include <hip/hip_runtime.h>

// ShortConvolution: depthwise causal conv1d (K=4) + SiLU
// x: (B=4, T=4096, D=2048) fp32, weight: (D, K) fp32, out: (B, T, D) fp32
// y[b,t,d] = silu( sum_k w[d,k] * x[b, t-3+k, d] )   (x[t<0] = 0)
//
// R1: batch-load structure. Each block covers one D-row (512 thr x float4)
// and TC=8 timesteps. All TC+3=11 window rows are loaded into a register
// array FIRST (11 independent dwordx4 loads in flight per wave), then the
// 8 outputs are computed+stored. Fixes the R0 latency-bound serialization
// (VGPR=32, one load in flight, 2.5 TB/s).

#define B_DIM 4
#define T_DIM 4096
#define D_DIM 2048
#define K_DIM 4
#define TC    8                // timesteps per block

typedef float f4_t __attribute__((ext_vector_type(4)));

__global__ __launch_bounds__(512) void shortconv_silu_kernel(
    const float* __restrict__ x,
    const float* __restrict__ w,
    float* __restrict__ out)
{
    const int n_chunks = T_DIM / TC;          // 512
    const int b  = blockIdx.x / n_chunks;
    const int c  = blockIdx.x % n_chunks;
    const int t0 = c * TC;
    const int d4 = threadIdx.x;               // float4 index over D
    const int d0 = d4 * 4;

    // Per-thread weights: 4 channels x 4 taps = 16 consecutive floats (row-major (D,K))
    const f4_t q0 = *(const f4_t*)(w + (size_t)(d0 + 0) * K_DIM);
    const f4_t q1 = *(const f4_t*)(w + (size_t)(d0 + 1) * K_DIM);
    const f4_t q2 = *(const f4_t*)(w + (size_t)(d0 + 2) * K_DIM);
    const f4_t q3 = *(const f4_t*)(w + (size_t)(d0 + 3) * K_DIM);

    const int rowstride = D_DIM / 4;          // float4 elements per time row
    const f4_t* xv = (const f4_t*)(x   + (size_t)b * T_DIM * D_DIM) + d4;
    f4_t*       ov = (f4_t*)      (out + (size_t)b * T_DIM * D_DIM) + d4;

    // ---- Phase 1: batch-load the whole window (TC+3 rows) ----
    f4_t r[TC + 3];
    if (c == 0) {
        r[0] = (f4_t)0.f;
        r[1] = (f4_t)0.f;
        r[2] = (f4_t)0.f;
    } else {
        r[0] = xv[(size_t)(t0 - 3) * rowstride];
        r[1] = xv[(size_t)(t0 - 2) * rowstride];
        r[2] = xv[(size_t)(t0 - 1) * rowstride];
    }
#pragma unroll
    for (int i = 3; i < TC + 3; ++i) {
        r[i] = xv[(size_t)(t0 + i - 3) * rowstride];
    }

    // ---- Phase 2: compute + store ----
#pragma unroll
    for (int i = 0; i < TC; ++i) {
        const f4_t a = r[i], bb = r[i + 1], cc = r[i + 2], dd = r[i + 3];
        f4_t y;
        y.x = q0.x * a.x + q0.y * bb.x + q0.z * cc.x + q0.w * dd.x;
        y.y = q1.x * a.y + q1.y * bb.y + q1.z * cc.y + q1.w * dd.y;
        y.z = q2.x * a.z + q2.y * bb.z + q2.z * cc.z + q2.w * dd.z;
        y.w = q3.x * a.w + q3.y * bb.w + q3.z * cc.w + q3.w * dd.w;

        // SiLU: y / (1 + exp(-y))
        y.x = y.x / (1.f + __expf(-y.x));
        y.y = y.y / (1.f + __expf(-y.y));
        y.z = y.z / (1.f + __expf(-y.z));
        y.w = y.w / (1.f + __expf(-y.w));

        // Nontemporal store: streaming output, don't evict x halos from L2
        __builtin_nontemporal_store(y, &ov[(size_t)(t0 + i) * rowstride]);
    }
}

extern "C" void kernel_launch(void* const* d_in, const int* in_sizes, int n_in,
                              void* d_out, int out_size, void* d_ws, size_t ws_size,
                              hipStream_t stream) {
    const float* x = (const float*)d_in[0];
    const float* w = (const float*)d_in[1];
    float* out = (float*)d_out;

    const int n_chunks = T_DIM / TC;            // 512
    dim3 grid(B_DIM * n_chunks);                // 2048 blocks
    dim3 block(D_DIM / 4);                      // 512 threads
    shortconv_silu_kernel<<<grid, block, 0, stream>>>(x, w, out);
}

// Round 3
// 230.292 us; speedup vs baseline: 1.0364x; 1.0017x over previous
//
#include <hip/hip_runtime.h>

// ShortConvolution: depthwise causal conv1d (K=4) + SiLU
// x: (B=4, T=4096, D=2048) fp32, weight: (D, K) fp32, out: (B, T, D) fp32
// y[b,t,d] = silu( sum_k w[d,k] * x[b, t-3+k, d] )   (x[t<0] = 0)
//
// R2: R1's batch-load was defeated by the compiler sinking loads to their
// uses (VGPR stayed 32 -> 1-2 loads in flight -> 2.8 TB/s latency-bound).
// Fix: __builtin_amdgcn_sched_barrier(0) between load phase and compute
// phase pins all 11 global_load_dwordx4 before any FMA. Harness memset in
// the same trace ran 6.65 TB/s, so the BW target is ~6+ TB/s.

#define B_DIM 4
#define T_DIM 4096
#define D_DIM 2048
#define K_DIM 4
#define TC    8                // timesteps per block

typedef float f4_t __attribute__((ext_vector_type(4)));

__global__ __launch_bounds__(512) void shortconv_silu_kernel(
    const float* __restrict__ x,
    const float* __restrict__ w,
    float* __restrict__ out)
{
    const int n_chunks = T_DIM / TC;          // 512
    const int b  = blockIdx.x / n_chunks;
    const int c  = blockIdx.x % n_chunks;
    const int t0 = c * TC;
    const int d4 = threadIdx.x;               // float4 index over D
    const int d0 = d4 * 4;

    const int rowstride = D_DIM / 4;          // float4 elements per time row
    const f4_t* xv = (const f4_t*)(x   + (size_t)b * T_DIM * D_DIM) + d4;
    f4_t*       ov = (f4_t*)      (out + (size_t)b * T_DIM * D_DIM) + d4;

    // ---- Phase 1: issue ALL window loads (TC+3 rows) + weight loads ----
    f4_t r[TC + 3];
    if (c == 0) {
        r[0] = (f4_t)0.f;
        r[1] = (f4_t)0.f;
        r[2] = (f4_t)0.f;
    } else {
        r[0] = xv[(size_t)(t0 - 3) * rowstride];
        r[1] = xv[(size_t)(t0 - 2) * rowstride];
        r[2] = xv[(size_t)(t0 - 1) * rowstride];
    }
#pragma unroll
    for (int i = 3; i < TC + 3; ++i) {
        r[i] = xv[(size_t)(t0 + i - 3) * rowstride];
    }

    // Per-thread weights: 4 channels x 4 taps = 16 consecutive floats (row-major (D,K))
    const f4_t q0 = *(const f4_t*)(w + (size_t)(d0 + 0) * K_DIM);
    const f4_t q1 = *(const f4_t*)(w + (size_t)(d0 + 1) * K_DIM);
    const f4_t q2 = *(const f4_t*)(w + (size_t)(d0 + 2) * K_DIM);
    const f4_t q3 = *(const f4_t*)(w + (size_t)(d0 + 3) * K_DIM);

    // Hard scheduling fence: nothing moves across. All loads above are now
    // issued before any compute below -> 11+ loads in flight per wave.
    __builtin_amdgcn_sched_barrier(0);

    // ---- Phase 2: compute + store ----
#pragma unroll
    for (int i = 0; i < TC; ++i) {
        const f4_t a = r[i], bb = r[i + 1], cc = r[i + 2], dd = r[i + 3];
        f4_t y;
        y.x = q0.x * a.x + q0.y * bb.x + q0.z * cc.x + q0.w * dd.x;
        y.y = q1.x * a.y + q1.y * bb.y + q1.z * cc.y + q1.w * dd.y;
        y.z = q2.x * a.z + q2.y * bb.z + q2.z * cc.z + q2.w * dd.z;
        y.w = q3.x * a.w + q3.y * bb.w + q3.z * cc.w + q3.w * dd.w;

        // SiLU: y / (1 + exp(-y))
        y.x = y.x / (1.f + __expf(-y.x));
        y.y = y.y / (1.f + __expf(-y.y));
        y.z = y.z / (1.f + __expf(-y.z));
        y.w = y.w / (1.f + __expf(-y.w));

        // Nontemporal store: streaming output, don't evict x halos from L2
        __builtin_nontemporal_store(y, &ov[(size_t)(t0 + i) * rowstride]);
    }
}

extern "C" void kernel_launch(void* const* d_in, const int* in_sizes, int n_in,
                              void* d_out, int out_size, void* d_ws, size_t ws_size,
                              hipStream_t stream) {
    const float* x = (const float*)d_in[0];
    const float* w = (const float*)d_in[1];
    float* out = (float*)d_out;

    const int n_chunks = T_DIM / TC;            // 512
    dim3 grid(B_DIM * n_chunks);                // 2048 blocks
    dim3 block(D_DIM / 4);                      // 512 threads
    shortconv_silu_kernel<<<grid, block, 0, stream>>>(x, w, out);
}